// Round 9
// baseline (21.693 us; speedup 1.0000x reference)
//
#include <hip/hip_runtime.h>

// x: (49, 6, 256, 256) fp32; out: (6, 1024, 1024) fp32
// out[bc,h,w] = max over covering patches (i,j) of x[i*7+j, bc, h-128i, w-128j]
//
// R8 access pattern (4-row x float4 quad per thread, 16 B lane stride,
// 4 KB contiguous burst per (i,j) stream visit) + 256-thread blocks:
// 1536 blocks = exactly 6 blocks/CU = 24 waves/CU, all co-resident in one
// round (R8's 6144x64 needed 24 wg/CU, above the ~16 wg/CU HW cap ->
// second half-empty round). Loads are nontemporal: every line is consumed
// exactly once, so skip L2 allocation churn.

typedef float v4f __attribute__((ext_vector_type(4)));

__global__ __launch_bounds__(256) void unpatch_max_kernel(
    const float* __restrict__ x, float* __restrict__ out)
{
    const int tid = blockIdx.x * 256 + threadIdx.x;   // [0, 393216)
    const int w4   = tid & 255;          // float4 col in [0,256)
    const int rest = tid >> 8;
    const int rq   = rest & 255;         // row quad in [0,256)
    const int bc   = rest >> 8;          // in [0,6)

    const int h0 = rq << 2;              // first of 4 rows (4-aligned: never
                                         // straddles a 128-row band)
    const int w  = w4 << 2;

    const int hi = h0 >> 7;
    const int i1 = hi < 7 ? hi : 6;
    const int i0 = hi > 0 ? hi - 1 : 0;
    const int wi = w >> 7;
    const int j1 = wi < 7 ? wi : 6;
    const int j0 = wi > 0 ? wi - 1 : 0;

    v4f m0 = (v4f){-INFINITY, -INFINITY, -INFINITY, -INFINITY};
    v4f m1 = m0, m2 = m0, m3 = m0;

    #pragma unroll 2
    for (int i = i0; i <= i1; ++i) {
        const int ph0 = h0 - i * 128;                // in [0,256), 4-aligned
        #pragma unroll 2
        for (int j = j0; j <= j1; ++j) {
            const int pw  = w - j * 128;             // in [0,252], 4-aligned
            const float* p = x +
                ((size_t)((i * 7 + j) * 6 + bc) << 16) + (size_t)ph0 * 256 + pw;
            // 4 consecutive patch rows -> 4 KB contiguous per wave stream
            const v4f a0 = __builtin_nontemporal_load(reinterpret_cast<const v4f*>(p));
            const v4f a1 = __builtin_nontemporal_load(reinterpret_cast<const v4f*>(p + 256));
            const v4f a2 = __builtin_nontemporal_load(reinterpret_cast<const v4f*>(p + 512));
            const v4f a3 = __builtin_nontemporal_load(reinterpret_cast<const v4f*>(p + 768));
            m0 = __builtin_elementwise_max(m0, a0);
            m1 = __builtin_elementwise_max(m1, a1);
            m2 = __builtin_elementwise_max(m2, a2);
            m3 = __builtin_elementwise_max(m3, a3);
        }
    }

    float* o = out + ((size_t)bc << 20) + (size_t)h0 * 1024 + w;
    __builtin_nontemporal_store(m0, reinterpret_cast<v4f*>(o));
    __builtin_nontemporal_store(m1, reinterpret_cast<v4f*>(o + 1024));
    __builtin_nontemporal_store(m2, reinterpret_cast<v4f*>(o + 2048));
    __builtin_nontemporal_store(m3, reinterpret_cast<v4f*>(o + 3072));
}

extern "C" void kernel_launch(void* const* d_in, const int* in_sizes, int n_in,
                              void* d_out, int out_size, void* d_ws, size_t ws_size,
                              hipStream_t stream)
{
    const float* x = (const float*)d_in[0];
    float* out = (float*)d_out;

    // 393216 threads / 256 = 1536 blocks = 6 blocks/CU, all co-resident.
    unpatch_max_kernel<<<1536, 256, 0, stream>>>(x, out);
}